// Round 1
// baseline (191.091 us; speedup 1.0000x reference)
//
#include <hip/hip_runtime.h>
#include <hip/hip_bf16.h>
#include <math.h>

#define N_NODES 20000
#define N_EDGES 640000
#define D 128
#define GROWS 16

// ---------------- h = x @ W^T + b ----------------
__global__ __launch_bounds__(256) void linear_kernel(
    const float* __restrict__ x, const float* __restrict__ W,
    const float* __restrict__ b, float* __restrict__ h) {
  __shared__ float Ws[D][D + 1];   // +1 pad -> bank (o+k)%32: 2 lanes/bank, free
  __shared__ float xs[GROWS][D];
  const int tid = threadIdx.x;
  for (int idx = tid; idx < D * D; idx += 256)
    Ws[idx >> 7][idx & 127] = W[idx];
  const int row0 = blockIdx.x * GROWS;
  for (int idx = tid; idx < GROWS * D; idx += 256)
    xs[idx >> 7][idx & 127] = x[row0 * D + idx];
  __syncthreads();

  const int o = tid & 127;
  const int rh = tid >> 7;  // 0 or 1
  float acc[GROWS / 2];
#pragma unroll
  for (int j = 0; j < GROWS / 2; ++j) acc[j] = 0.f;
  for (int k = 0; k < D; ++k) {
    const float wv = Ws[o][k];
#pragma unroll
    for (int j = 0; j < GROWS / 2; ++j)
      acc[j] += xs[rh + 2 * j][k] * wv;
  }
  const float bias = b[o];
#pragma unroll
  for (int j = 0; j < GROWS / 2; ++j)
    h[(size_t)(row0 + rh + 2 * j) * D + o] = acc[j] + bias;
}

// ---------------- CSR build ----------------
__global__ void count_kernel(const int* __restrict__ rows, int* __restrict__ cnt) {
  const int e = blockIdx.x * blockDim.x + threadIdx.x;
  if (e < N_EDGES) atomicAdd(&cnt[rows[e]], 1);
}

__global__ __launch_bounds__(1024) void scan_kernel(
    const int* __restrict__ cnt, int* __restrict__ rowptr, int* __restrict__ cursor) {
  __shared__ int buf[1024];
  __shared__ int carry_s;
  const int tid = threadIdx.x;
  if (tid == 0) { carry_s = 0; rowptr[0] = 0; }
  __syncthreads();
  for (int base = 0; base < N_NODES; base += 1024) {
    const int i = base + tid;
    const int v = (i < N_NODES) ? cnt[i] : 0;
    buf[tid] = v;
    __syncthreads();
    for (int off = 1; off < 1024; off <<= 1) {
      const int t = (tid >= off) ? buf[tid - off] : 0;
      __syncthreads();
      buf[tid] += t;
      __syncthreads();
    }
    const int incl = buf[tid];
    if (i < N_NODES) {
      rowptr[i + 1] = carry_s + incl;
      cursor[i] = carry_s + incl - v;  // exclusive prefix = fill start
    }
    __syncthreads();
    if (tid == 1023) carry_s += buf[1023];
    __syncthreads();
  }
}

__global__ void fill_kernel(const int* __restrict__ rows, const int* __restrict__ cols,
                            const float* __restrict__ ew, int* __restrict__ cursor,
                            int* __restrict__ colidx, float* __restrict__ wval) {
  const int e = blockIdx.x * blockDim.x + threadIdx.x;
  if (e < N_EDGES) {
    const int r = rows[e];
    const int p = atomicAdd(&cursor[r], 1);
    colidx[p] = cols[e];
    wval[p] = ew[e];
  }
}

// ---------------- gather aggregation + mean + L2 normalize ----------------
// one wave per node; lane owns 2 of the 128 features (float2 = 512B/wave coalesced)
__global__ __launch_bounds__(256) void agg_kernel(
    const float* __restrict__ h, const int* __restrict__ rowptr,
    const int* __restrict__ colidx, const float* __restrict__ wval,
    float* __restrict__ out) {
  const int node = blockIdx.x * 4 + (threadIdx.x >> 6);
  const int lane = threadIdx.x & 63;
  if (node >= N_NODES) return;
  const int e0 = rowptr[node];
  const int e1 = rowptr[node + 1];
  float a0 = 0.f, a1 = 0.f, dw = 0.f;
  int e = e0;
  for (; e + 3 < e1; e += 4) {  // 4 gathers in flight
    const int c0 = colidx[e], c1 = colidx[e + 1], c2 = colidx[e + 2], c3 = colidx[e + 3];
    const float w0 = wval[e], w1 = wval[e + 1], w2 = wval[e + 2], w3 = wval[e + 3];
    const float2 v0 = *reinterpret_cast<const float2*>(&h[(size_t)c0 * D + lane * 2]);
    const float2 v1 = *reinterpret_cast<const float2*>(&h[(size_t)c1 * D + lane * 2]);
    const float2 v2 = *reinterpret_cast<const float2*>(&h[(size_t)c2 * D + lane * 2]);
    const float2 v3 = *reinterpret_cast<const float2*>(&h[(size_t)c3 * D + lane * 2]);
    a0 += v0.x * w0; a1 += v0.y * w0;
    a0 += v1.x * w1; a1 += v1.y * w1;
    a0 += v2.x * w2; a1 += v2.y * w2;
    a0 += v3.x * w3; a1 += v3.y * w3;
    dw += w0 + w1 + w2 + w3;
  }
  for (; e < e1; ++e) {
    const int c = colidx[e];
    const float w = wval[e];
    const float2 v = *reinterpret_cast<const float2*>(&h[(size_t)c * D + lane * 2]);
    a0 += v.x * w; a1 += v.y * w; dw += w;
  }
  const float dinv = dw > 0.f ? 1.f / dw : 0.f;
  const float o0 = a0 * dinv, o1 = a1 * dinv;
  float ss = o0 * o0 + o1 * o1;
#pragma unroll
  for (int off = 1; off < 64; off <<= 1) ss += __shfl_xor(ss, off);
  const float scale = 1.f / fmaxf(sqrtf(ss), 1e-12f);
  *reinterpret_cast<float2*>(&out[(size_t)node * D + lane * 2]) =
      make_float2(o0 * scale, o1 * scale);
}

// ---------------- fallback (small ws): atomic scatter ----------------
__global__ __launch_bounds__(256) void scatter_kernel(
    const float* __restrict__ h, const int* __restrict__ rows, const int* __restrict__ cols,
    const float* __restrict__ ew, float* __restrict__ agg, float* __restrict__ deg) {
  const int e = blockIdx.x * 4 + (threadIdx.x >> 6);
  const int lane = threadIdx.x & 63;
  if (e >= N_EDGES) return;
  const int r = rows[e];
  const int c = cols[e];
  const float w = ew[e];
  const float2 v = *reinterpret_cast<const float2*>(&h[(size_t)c * D + lane * 2]);
  atomicAdd(&agg[(size_t)r * D + lane * 2], v.x * w);
  atomicAdd(&agg[(size_t)r * D + lane * 2 + 1], v.y * w);
  if (lane == 0) atomicAdd(&deg[r], w);
}

__global__ __launch_bounds__(256) void normalize_kernel(float* __restrict__ out,
                                                        const float* __restrict__ deg) {
  const int node = blockIdx.x * 4 + (threadIdx.x >> 6);
  const int lane = threadIdx.x & 63;
  if (node >= N_NODES) return;
  const float2 v = *reinterpret_cast<const float2*>(&out[(size_t)node * D + lane * 2]);
  const float dw = deg[node];
  const float dinv = dw > 0.f ? 1.f / dw : 0.f;
  const float o0 = v.x * dinv, o1 = v.y * dinv;
  float ss = o0 * o0 + o1 * o1;
#pragma unroll
  for (int off = 1; off < 64; off <<= 1) ss += __shfl_xor(ss, off);
  const float scale = 1.f / fmaxf(sqrtf(ss), 1e-12f);
  *reinterpret_cast<float2*>(&out[(size_t)node * D + lane * 2]) =
      make_float2(o0 * scale, o1 * scale);
}

extern "C" void kernel_launch(void* const* d_in, const int* in_sizes, int n_in,
                              void* d_out, int out_size, void* d_ws, size_t ws_size,
                              hipStream_t stream) {
  const float* x  = (const float*)d_in[0];
  const int*   ei = (const int*)d_in[1];
  const float* ew = (const float*)d_in[2];
  const float* W  = (const float*)d_in[3];
  const float* b  = (const float*)d_in[4];
  float* out = (float*)d_out;
  char* ws = (char*)d_ws;

  const int* rows = ei;
  const int* cols = ei + N_EDGES;

  // workspace layout
  size_t off = 0;
  float* h = (float*)(ws + off);      off += (size_t)N_NODES * D * 4;   // 10.24 MB
  int* rowptr = (int*)(ws + off);     off += ((size_t)N_NODES + 1) * 4;
  off = (off + 15) & ~(size_t)15;
  int* cnt = (int*)(ws + off);        off += (size_t)N_NODES * 4;
  int* cursor = (int*)(ws + off);     off += (size_t)N_NODES * 4;
  int* colidx = (int*)(ws + off);     off += (size_t)N_EDGES * 4;
  float* wval = (float*)(ws + off);   off += (size_t)N_EDGES * 4;
  const size_t csr_bytes = off;
  const size_t fallback_bytes = (size_t)N_NODES * D * 4 + (size_t)N_NODES * 4;

  linear_kernel<<<N_NODES / GROWS, 256, 0, stream>>>(x, W, b, h);

  if (ws_size >= csr_bytes) {
    hipMemsetAsync(cnt, 0, (size_t)N_NODES * 4, stream);
    count_kernel<<<(N_EDGES + 255) / 256, 256, 0, stream>>>(rows, cnt);
    scan_kernel<<<1, 1024, 0, stream>>>(cnt, rowptr, cursor);
    fill_kernel<<<(N_EDGES + 255) / 256, 256, 0, stream>>>(rows, cols, ew, cursor,
                                                           colidx, wval);
    agg_kernel<<<(N_NODES + 3) / 4, 256, 0, stream>>>(h, rowptr, colidx, wval, out);
  } else if (ws_size >= fallback_bytes) {
    float* deg = (float*)(ws + (size_t)N_NODES * D * 4);
    hipMemsetAsync(out, 0, (size_t)N_NODES * D * 4, stream);
    hipMemsetAsync(deg, 0, (size_t)N_NODES * 4, stream);
    scatter_kernel<<<(N_EDGES + 3) / 4, 256, 0, stream>>>(h, rows, cols, ew, out, deg);
    normalize_kernel<<<(N_NODES + 3) / 4, 256, 0, stream>>>(out, deg);
  }
}

// Round 2
// 117.716 us; speedup vs baseline: 1.6233x; 1.6233x over previous
//
#include <hip/hip_runtime.h>
#include <hip/hip_bf16.h>
#include <math.h>

#define N_NODES 20000
#define N_EDGES 640000
#define D 128
#define GROWS 16
#define STRIDE 96   // max supported degree; Binomial(640k,1/20k) max ~57, huge margin

// ---------------- strided CSR-free fill: colw[node][p] = (col, w_bits) ----------------
__global__ __launch_bounds__(256) void fill_kernel(
    const int* __restrict__ rows, const int* __restrict__ cols,
    const float* __restrict__ ew, int* __restrict__ cnt, int2* __restrict__ colw) {
  const int e = blockIdx.x * 256 + threadIdx.x;
  if (e >= N_EDGES) return;
  const int r = rows[e];
  const int p = atomicAdd(&cnt[r], 1);
  if (p < STRIDE)
    colw[(size_t)r * STRIDE + p] = make_int2(cols[e], __float_as_int(ew[e]));
}

// ---------------- gather weighted-SUM of x into out, degw per node ----------------
// one wave per node; lane owns 2 of 128 features (float2 = 512B/wave coalesced)
__global__ __launch_bounds__(256) void agg_kernel(
    const float* __restrict__ x, const int* __restrict__ cnt,
    const int2* __restrict__ colw, float* __restrict__ out,
    float* __restrict__ degw) {
  const int node = blockIdx.x * 4 + (threadIdx.x >> 6);
  const int lane = threadIdx.x & 63;
  if (node >= N_NODES) return;
  int n = cnt[node];
  if (n > STRIDE) n = STRIDE;
  const int2* __restrict__ seg = colw + (size_t)node * STRIDE;
  float a0 = 0.f, a1 = 0.f, dw = 0.f;
  int e = 0;
  for (; e + 3 < n; e += 4) {  // 4 gathers in flight
    const int2 c0 = seg[e], c1 = seg[e + 1], c2 = seg[e + 2], c3 = seg[e + 3];
    const float w0 = __int_as_float(c0.y), w1 = __int_as_float(c1.y);
    const float w2 = __int_as_float(c2.y), w3 = __int_as_float(c3.y);
    const float2 v0 = *reinterpret_cast<const float2*>(&x[(size_t)c0.x * D + lane * 2]);
    const float2 v1 = *reinterpret_cast<const float2*>(&x[(size_t)c1.x * D + lane * 2]);
    const float2 v2 = *reinterpret_cast<const float2*>(&x[(size_t)c2.x * D + lane * 2]);
    const float2 v3 = *reinterpret_cast<const float2*>(&x[(size_t)c3.x * D + lane * 2]);
    a0 += v0.x * w0; a1 += v0.y * w0;
    a0 += v1.x * w1; a1 += v1.y * w1;
    a0 += v2.x * w2; a1 += v2.y * w2;
    a0 += v3.x * w3; a1 += v3.y * w3;
    dw += w0 + w1 + w2 + w3;
  }
  for (; e < n; ++e) {
    const int2 c = seg[e];
    const float w = __int_as_float(c.y);
    const float2 v = *reinterpret_cast<const float2*>(&x[(size_t)c.x * D + lane * 2]);
    a0 += v.x * w; a1 += v.y * w; dw += w;
  }
  if (lane == 0) degw[node] = dw;
  *reinterpret_cast<float2*>(&out[(size_t)node * D + lane * 2]) = make_float2(a0, a1);
}

// ---------------- mean-scale -> GEMV(W^T) + b -> L2 normalize, in-place on out ----------------
__global__ __launch_bounds__(256) void linear_norm_kernel(
    const float* __restrict__ W, const float* __restrict__ b,
    const float* __restrict__ degw, float* __restrict__ out) {
  __shared__ float Ws[D][D + 1];   // +1 pad -> (o+k)%32 banks, conflict-free
  __shared__ float xs[GROWS][D];
  __shared__ float dws[GROWS];
  const int tid = threadIdx.x;
  const int row0 = blockIdx.x * GROWS;
  for (int idx = tid; idx < D * D; idx += 256)
    Ws[idx >> 7][idx & 127] = W[idx];
  if (tid < GROWS) dws[tid] = degw[row0 + tid];
  __syncthreads();
  for (int idx = tid; idx < GROWS * D; idx += 256) {
    const int r = idx >> 7;
    const float dw = dws[r];
    const float dinv = dw > 0.f ? 1.f / dw : 0.f;
    xs[r][idx & 127] = out[(size_t)(row0 + r) * D + (idx & 127)] * dinv;  // mean
  }
  __syncthreads();

  const int o = tid & 127;
  const int rh = tid >> 7;  // 0 or 1
  float acc[GROWS / 2];
#pragma unroll
  for (int j = 0; j < GROWS / 2; ++j) acc[j] = 0.f;
  for (int k = 0; k < D; ++k) {
    const float wv = Ws[o][k];
#pragma unroll
    for (int j = 0; j < GROWS / 2; ++j)
      acc[j] += xs[rh + 2 * j][k] * wv;
  }
  const float bias = b[o];
  __syncthreads();  // all xs reads done; reuse xs as output stage
#pragma unroll
  for (int j = 0; j < GROWS / 2; ++j)
    xs[rh + 2 * j][o] = acc[j] + bias;
  __syncthreads();

  // normalize: 4 waves x 4 rows each
  const int w = tid >> 6, lane = tid & 63;
#pragma unroll
  for (int q = 0; q < 4; ++q) {
    const int r = w * 4 + q;
    const float2 v = *reinterpret_cast<const float2*>(&xs[r][lane * 2]);
    float ss = v.x * v.x + v.y * v.y;
#pragma unroll
    for (int off = 1; off < 64; off <<= 1) ss += __shfl_xor(ss, off);
    const float dw = dws[r];
    const float scale = (dw > 0.f) ? 1.f / fmaxf(sqrtf(ss), 1e-12f) : 0.f;
    *reinterpret_cast<float2*>(&out[(size_t)(row0 + r) * D + lane * 2]) =
        make_float2(v.x * scale, v.y * scale);
  }
}

// ---------------- fallback (small ws): atomic scatter of x into out ----------------
__global__ __launch_bounds__(256) void scatter_kernel(
    const float* __restrict__ x, const int* __restrict__ rows,
    const int* __restrict__ cols, const float* __restrict__ ew,
    float* __restrict__ out, float* __restrict__ degw) {
  const int e = blockIdx.x * 4 + (threadIdx.x >> 6);
  const int lane = threadIdx.x & 63;
  if (e >= N_EDGES) return;
  const int r = rows[e];
  const int c = cols[e];
  const float w = ew[e];
  const float2 v = *reinterpret_cast<const float2*>(&x[(size_t)c * D + lane * 2]);
  atomicAdd(&out[(size_t)r * D + lane * 2], v.x * w);
  atomicAdd(&out[(size_t)r * D + lane * 2 + 1], v.y * w);
  if (lane == 0) atomicAdd(&degw[r], w);
}

extern "C" void kernel_launch(void* const* d_in, const int* in_sizes, int n_in,
                              void* d_out, int out_size, void* d_ws, size_t ws_size,
                              hipStream_t stream) {
  const float* x  = (const float*)d_in[0];
  const int*   ei = (const int*)d_in[1];
  const float* ew = (const float*)d_in[2];
  const float* W  = (const float*)d_in[3];
  const float* b  = (const float*)d_in[4];
  float* out = (float*)d_out;
  char* ws = (char*)d_ws;

  const int* rows = ei;
  const int* cols = ei + N_EDGES;

  // ws layout
  size_t off = 0;
  int* cnt = (int*)(ws + off);      off += (size_t)N_NODES * 4;          // 80 KB
  float* degw = (float*)(ws + off); off += (size_t)N_NODES * 4;          // 80 KB
  int2* colw = (int2*)(ws + off);   off += (size_t)N_NODES * STRIDE * 8; // 15.36 MB
  const size_t main_bytes = off;
  const size_t fallback_bytes = (size_t)N_NODES * 4 * 2;

  if (ws_size >= main_bytes) {
    hipMemsetAsync(cnt, 0, (size_t)N_NODES * 4, stream);
    fill_kernel<<<(N_EDGES + 255) / 256, 256, 0, stream>>>(rows, cols, ew, cnt, colw);
    agg_kernel<<<(N_NODES + 3) / 4, 256, 0, stream>>>(x, cnt, colw, out, degw);
    linear_norm_kernel<<<N_NODES / GROWS, 256, 0, stream>>>(W, b, degw, out);
  } else if (ws_size >= fallback_bytes) {
    hipMemsetAsync(out, 0, (size_t)N_NODES * D * 4, stream);
    hipMemsetAsync(degw, 0, (size_t)N_NODES * 4, stream);
    scatter_kernel<<<(N_EDGES + 3) / 4, 256, 0, stream>>>(x, rows, cols, ew, out, degw);
    linear_norm_kernel<<<N_NODES / GROWS, 256, 0, stream>>>(W, b, degw, out);
  }
}

// Round 3
// 108.101 us; speedup vs baseline: 1.7677x; 1.0889x over previous
//
#include <hip/hip_runtime.h>
#include <hip/hip_bf16.h>
#include <math.h>

#define N_NODES 20000
#define N_EDGES 640000
#define D 128
#define GROWS 16

#define BSHIFT 5
#define BNODES (1 << BSHIFT)              // 32 nodes per bucket
#define NBUCK (N_NODES >> BSHIFT)         // 625 exactly
#define CAP 1536                          // per-bucket cap (mean 1024, sd ~32)
#define RPT ((CAP + 255) / 256)           // 6 edges/thread in agg sort
#define NBLK1 160
#define CHUNK ((N_EDGES + NBLK1 - 1) / NBLK1)  // 4000

// ---- phase 1: bin edges by node-bucket, contiguous bucket writes ----
__global__ __launch_bounds__(256) void bin_kernel(
    const int* __restrict__ rows, const int* __restrict__ cols,
    const float* __restrict__ ew, int* __restrict__ gcur,
    uint2* __restrict__ bins) {
  __shared__ int cnt[NBUCK];
  __shared__ int base[NBUCK];
  const int tid = threadIdx.x;
  const int e0 = blockIdx.x * CHUNK;
  const int e1 = min(e0 + CHUNK, N_EDGES);
  for (int i = tid; i < NBUCK; i += 256) cnt[i] = 0;
  __syncthreads();
  for (int e = e0 + tid; e < e1; e += 256)
    atomicAdd(&cnt[rows[e] >> BSHIFT], 1);
  __syncthreads();
  for (int i = tid; i < NBUCK; i += 256) {
    const int c = cnt[i];
    base[i] = c ? atomicAdd(&gcur[i], c) : 0;
  }
  __syncthreads();
  for (int i = tid; i < NBUCK; i += 256) cnt[i] = 0;
  __syncthreads();
  for (int e = e0 + tid; e < e1; e += 256) {
    const int r = rows[e];
    const int b = r >> BSHIFT;
    const int p = base[b] + atomicAdd(&cnt[b], 1);
    if (p < CAP)  // bucket overflow guard (statistically impossible)
      bins[(size_t)b * CAP + p] =
          make_uint2(((unsigned)(r & (BNODES - 1)) << 16) | (unsigned)cols[e],
                     __float_as_uint(ew[e]));
  }
}

// ---- phase 2: per-bucket LDS counting sort + gather aggregation ----
__global__ __launch_bounds__(256) void agg_kernel(
    const float* __restrict__ x, const int* __restrict__ gcur,
    const uint2* __restrict__ bins, float* __restrict__ out,
    float* __restrict__ degw) {
  __shared__ uint2 list[CAP];
  __shared__ int cnt[BNODES];
  __shared__ int base[BNODES];
  const int b = blockIdx.x;
  const int tid = threadIdx.x;
  const int n = min(gcur[b], CAP);
  if (tid < BNODES) cnt[tid] = 0;
  __syncthreads();

  uint2 ebuf[RPT];
  int rkbuf[RPT], rlbuf[RPT];
#pragma unroll
  for (int j = 0; j < RPT; ++j) {
    const int i = tid + j * 256;
    rlbuf[j] = -1;
    if (i < n) {
      const uint2 e = bins[(size_t)b * CAP + i];
      const int rl = e.x >> 16;
      ebuf[j] = e;
      rlbuf[j] = rl;
      rkbuf[j] = atomicAdd(&cnt[rl], 1);
    }
  }
  __syncthreads();
  if (tid == 0) {
    int s = 0;
#pragma unroll
    for (int i = 0; i < BNODES; ++i) { base[i] = s; s += cnt[i]; }
  }
  __syncthreads();
#pragma unroll
  for (int j = 0; j < RPT; ++j)
    if (rlbuf[j] >= 0) list[base[rlbuf[j]] + rkbuf[j]] = ebuf[j];
  __syncthreads();

  // 4 waves x 8 nodes each; lane owns 2 of 128 features
  const int wv = tid >> 6, lane = tid & 63;
  for (int q = 0; q < 8; ++q) {
    const int rl = wv * 8 + q;
    const int node = (b << BSHIFT) + rl;
    const int s = base[rl], cn = cnt[rl];
    float a0 = 0.f, a1 = 0.f, dw = 0.f;
    int k = s;
    const int ke = s + cn;
    for (; k + 7 < ke; k += 8) {  // 8 gathers in flight
      float2 v[8];
      float w[8];
#pragma unroll
      for (int u = 0; u < 8; ++u) {
        const uint2 e = list[k + u];
        w[u] = __uint_as_float(e.y);
        v[u] = *reinterpret_cast<const float2*>(
            &x[(size_t)(e.x & 0xffffu) * D + lane * 2]);
      }
#pragma unroll
      for (int u = 0; u < 8; ++u) {
        a0 += v[u].x * w[u]; a1 += v[u].y * w[u]; dw += w[u];
      }
    }
    for (; k < ke; ++k) {
      const uint2 e = list[k];
      const float w = __uint_as_float(e.y);
      const float2 v = *reinterpret_cast<const float2*>(
          &x[(size_t)(e.x & 0xffffu) * D + lane * 2]);
      a0 += v.x * w; a1 += v.y * w; dw += w;
    }
    if (lane == 0) degw[node] = dw;
    *reinterpret_cast<float2*>(&out[(size_t)node * D + lane * 2]) =
        make_float2(a0, a1);
  }
}

// ---- mean-scale -> GEMV(W^T)+b -> L2 normalize, in-place on out ----
__global__ __launch_bounds__(256) void linear_norm_kernel(
    const float* __restrict__ W, const float* __restrict__ b,
    const float* __restrict__ degw, float* __restrict__ out) {
  __shared__ float Ws[D][D + 1];
  __shared__ float xs[GROWS][D];
  __shared__ float dws[GROWS];
  const int tid = threadIdx.x;
  const int row0 = blockIdx.x * GROWS;
  for (int idx = tid; idx < D * D; idx += 256)
    Ws[idx >> 7][idx & 127] = W[idx];
  if (tid < GROWS) dws[tid] = degw[row0 + tid];
  __syncthreads();
  for (int idx = tid; idx < GROWS * D; idx += 256) {
    const int r = idx >> 7;
    const float dw = dws[r];
    const float dinv = dw > 0.f ? 1.f / dw : 0.f;
    xs[r][idx & 127] = out[(size_t)(row0 + r) * D + (idx & 127)] * dinv;
  }
  __syncthreads();

  const int o = tid & 127;
  const int rh = tid >> 7;
  float acc[GROWS / 2];
#pragma unroll
  for (int j = 0; j < GROWS / 2; ++j) acc[j] = 0.f;
  for (int k = 0; k < D; ++k) {
    const float wv = Ws[o][k];
#pragma unroll
    for (int j = 0; j < GROWS / 2; ++j)
      acc[j] += xs[rh + 2 * j][k] * wv;
  }
  const float bias = b[o];
  __syncthreads();
#pragma unroll
  for (int j = 0; j < GROWS / 2; ++j)
    xs[rh + 2 * j][o] = acc[j] + bias;
  __syncthreads();

  const int w = tid >> 6, lane = tid & 63;
#pragma unroll
  for (int q = 0; q < 4; ++q) {
    const int r = w * 4 + q;
    const float2 v = *reinterpret_cast<const float2*>(&xs[r][lane * 2]);
    float ss = v.x * v.x + v.y * v.y;
#pragma unroll
    for (int off = 1; off < 64; off <<= 1) ss += __shfl_xor(ss, off);
    const float dw = dws[r];
    const float scale = (dw > 0.f) ? 1.f / fmaxf(sqrtf(ss), 1e-12f) : 0.f;
    *reinterpret_cast<float2*>(&out[(size_t)(row0 + r) * D + lane * 2]) =
        make_float2(v.x * scale, v.y * scale);
  }
}

// ---- fallback (tiny ws): atomic scatter ----
__global__ __launch_bounds__(256) void scatter_kernel(
    const float* __restrict__ x, const int* __restrict__ rows,
    const int* __restrict__ cols, const float* __restrict__ ew,
    float* __restrict__ out, float* __restrict__ degw) {
  const int e = blockIdx.x * 4 + (threadIdx.x >> 6);
  const int lane = threadIdx.x & 63;
  if (e >= N_EDGES) return;
  const int r = rows[e];
  const int c = cols[e];
  const float w = ew[e];
  const float2 v = *reinterpret_cast<const float2*>(&x[(size_t)c * D + lane * 2]);
  atomicAdd(&out[(size_t)r * D + lane * 2], v.x * w);
  atomicAdd(&out[(size_t)r * D + lane * 2 + 1], v.y * w);
  if (lane == 0) atomicAdd(&degw[r], w);
}

extern "C" void kernel_launch(void* const* d_in, const int* in_sizes, int n_in,
                              void* d_out, int out_size, void* d_ws, size_t ws_size,
                              hipStream_t stream) {
  const float* x  = (const float*)d_in[0];
  const int*   ei = (const int*)d_in[1];
  const float* ew = (const float*)d_in[2];
  const float* W  = (const float*)d_in[3];
  const float* b  = (const float*)d_in[4];
  float* out = (float*)d_out;
  char* ws = (char*)d_ws;

  const int* rows = ei;
  const int* cols = ei + N_EDGES;

  // ws layout
  size_t off = 0;
  int* gcur = (int*)(ws + off);     off += ((size_t)NBUCK * 4 + 15) & ~(size_t)15;
  float* degw = (float*)(ws + off); off += (size_t)N_NODES * 4;           // 80 KB
  uint2* bins = (uint2*)(ws + off); off += (size_t)NBUCK * CAP * 8;       // 7.68 MB
  const size_t main_bytes = off;
  const size_t fallback_bytes = ((size_t)NBUCK * 4 + 15 & ~(size_t)15) + (size_t)N_NODES * 4;

  if (ws_size >= main_bytes) {
    hipMemsetAsync(gcur, 0, (size_t)NBUCK * 4, stream);
    bin_kernel<<<NBLK1, 256, 0, stream>>>(rows, cols, ew, gcur, bins);
    agg_kernel<<<NBUCK, 256, 0, stream>>>(x, gcur, bins, out, degw);
    linear_norm_kernel<<<N_NODES / GROWS, 256, 0, stream>>>(W, b, degw, out);
  } else if (ws_size >= fallback_bytes) {
    hipMemsetAsync(out, 0, (size_t)N_NODES * D * 4, stream);
    hipMemsetAsync(degw, 0, (size_t)N_NODES * 4, stream);
    scatter_kernel<<<(N_EDGES + 3) / 4, 256, 0, stream>>>(x, rows, cols, ew, out, degw);
    linear_norm_kernel<<<N_NODES / GROWS, 256, 0, stream>>>(W, b, degw, out);
  }
}

// Round 4
// 91.952 us; speedup vs baseline: 2.0782x; 1.1756x over previous
//
#include <hip/hip_runtime.h>
#include <hip/hip_bf16.h>
#include <math.h>

#define N_NODES 20000
#define N_EDGES 640000
#define D 128
#define GROWS 16

#define BSHIFT 5
#define BNODES (1 << BSHIFT)              // 32 nodes per bucket
#define NBUCK (N_NODES >> BSHIFT)         // 625 exactly
#define CAP 1536                          // per-bucket cap (mean 1024, sd ~32)
#define AGG_T 512
#define RPT ((CAP + AGG_T - 1) / AGG_T)   // 3
#define NBLK1 160
#define CHUNK ((N_EDGES + NBLK1 - 1) / NBLK1)  // 4000

static __device__ __forceinline__ unsigned short f2bf(float f) {
  unsigned u = __float_as_uint(f);
  return (unsigned short)((u + 0x7fffu + ((u >> 16) & 1u)) >> 16);
}

__global__ __launch_bounds__(256) void zero_kernel(int* __restrict__ p, int n) {
  const int i = blockIdx.x * 256 + threadIdx.x;
  if (i < n) p[i] = 0;
}

// ---- cast x (f32) -> packed bf16x2 rows (64 uints per node) ----
__global__ __launch_bounds__(256) void cast_kernel(
    const float* __restrict__ x, unsigned* __restrict__ xb) {
  const int i = blockIdx.x * 256 + threadIdx.x;   // one float4 -> one uint2
  if (i >= N_NODES * D / 4) return;
  const float4 v = *reinterpret_cast<const float4*>(&x[(size_t)i * 4]);
  uint2 o;
  o.x = (unsigned)f2bf(v.x) | ((unsigned)f2bf(v.y) << 16);
  o.y = (unsigned)f2bf(v.z) | ((unsigned)f2bf(v.w) << 16);
  *reinterpret_cast<uint2*>(&xb[(size_t)i * 2]) = o;
}

// ---- phase 1: bin edges by node-bucket, contiguous bucket writes ----
__global__ __launch_bounds__(256) void bin_kernel(
    const int* __restrict__ rows, const int* __restrict__ cols,
    const float* __restrict__ ew, int* __restrict__ gcur,
    uint2* __restrict__ bins) {
  __shared__ int cnt[NBUCK];
  __shared__ int base[NBUCK];
  const int tid = threadIdx.x;
  const int e0 = blockIdx.x * CHUNK;
  const int e1 = min(e0 + CHUNK, N_EDGES);
  for (int i = tid; i < NBUCK; i += 256) cnt[i] = 0;
  __syncthreads();
  for (int e = e0 + tid; e < e1; e += 256)
    atomicAdd(&cnt[rows[e] >> BSHIFT], 1);
  __syncthreads();
  for (int i = tid; i < NBUCK; i += 256) {
    const int c = cnt[i];
    base[i] = c ? atomicAdd(&gcur[i], c) : 0;
  }
  __syncthreads();
  for (int i = tid; i < NBUCK; i += 256) cnt[i] = 0;
  __syncthreads();
  for (int e = e0 + tid; e < e1; e += 256) {
    const int r = rows[e];
    const int b = r >> BSHIFT;
    const int p = base[b] + atomicAdd(&cnt[b], 1);
    if (p < CAP)  // bucket overflow guard (statistically impossible)
      bins[(size_t)b * CAP + p] =
          make_uint2(((unsigned)(r & (BNODES - 1)) << 16) | (unsigned)cols[e],
                     __float_as_uint(ew[e]));
  }
}

// ---- phase 2: per-bucket LDS counting sort + bf16 gather aggregation ----
__global__ __launch_bounds__(AGG_T) void agg_kernel(
    const unsigned* __restrict__ xb, const int* __restrict__ gcur,
    const uint2* __restrict__ bins, float* __restrict__ out,
    float* __restrict__ degw) {
  __shared__ uint2 list[CAP];
  __shared__ int cnt[BNODES];
  __shared__ int base[BNODES];
  const int b = blockIdx.x;
  const int tid = threadIdx.x;
  const int n = min(gcur[b], CAP);
  if (tid < BNODES) cnt[tid] = 0;
  __syncthreads();

  uint2 ebuf[RPT];
  int rkbuf[RPT], rlbuf[RPT];
#pragma unroll
  for (int j = 0; j < RPT; ++j) {
    const int i = tid + j * AGG_T;
    rlbuf[j] = -1;
    if (i < n) {
      const uint2 e = bins[(size_t)b * CAP + i];
      const int rl = e.x >> 16;
      ebuf[j] = e;
      rlbuf[j] = rl;
      rkbuf[j] = atomicAdd(&cnt[rl], 1);
    }
  }
  __syncthreads();
  if (tid == 0) {
    int s = 0;
#pragma unroll
    for (int i = 0; i < BNODES; ++i) { base[i] = s; s += cnt[i]; }
  }
  __syncthreads();
#pragma unroll
  for (int j = 0; j < RPT; ++j)
    if (rlbuf[j] >= 0) list[base[rlbuf[j]] + rkbuf[j]] = ebuf[j];
  __syncthreads();

  // 8 waves x 4 nodes each; lane owns 2 of 128 features (one bf16x2 word)
  const int wv = tid >> 6, lane = tid & 63;
  for (int q = 0; q < 4; ++q) {
    const int rl = wv * 4 + q;
    const int node = (b << BSHIFT) + rl;
    const int s = base[rl], cn = cnt[rl];
    float a0 = 0.f, a1 = 0.f, dw = 0.f;
    int k = s;
    const int ke = s + cn;
    for (; k + 7 < ke; k += 8) {  // 8 gathers in flight
      unsigned v[8];
      float w[8];
#pragma unroll
      for (int u = 0; u < 8; ++u) {
        const uint2 e = list[k + u];
        w[u] = __uint_as_float(e.y);
        v[u] = xb[(size_t)(e.x & 0xffffu) * (D / 2) + lane];
      }
#pragma unroll
      for (int u = 0; u < 8; ++u) {
        a0 += __uint_as_float(v[u] << 16) * w[u];
        a1 += __uint_as_float(v[u] & 0xffff0000u) * w[u];
        dw += w[u];
      }
    }
    for (; k < ke; ++k) {
      const uint2 e = list[k];
      const float w = __uint_as_float(e.y);
      const unsigned v = xb[(size_t)(e.x & 0xffffu) * (D / 2) + lane];
      a0 += __uint_as_float(v << 16) * w;
      a1 += __uint_as_float(v & 0xffff0000u) * w;
      dw += w;
    }
    if (lane == 0) degw[node] = dw;
    *reinterpret_cast<float2*>(&out[(size_t)node * D + lane * 2]) =
        make_float2(a0, a1);
  }
}

// ---- mean-scale -> GEMV(W^T)+b -> L2 normalize, in-place on out ----
__global__ __launch_bounds__(256) void linear_norm_kernel(
    const float* __restrict__ W, const float* __restrict__ b,
    const float* __restrict__ degw, float* __restrict__ out) {
  __shared__ float Ws[D][D + 1];
  __shared__ float xs[GROWS][D];
  __shared__ float dws[GROWS];
  const int tid = threadIdx.x;
  const int row0 = blockIdx.x * GROWS;
  for (int idx = tid; idx < D * D; idx += 256)
    Ws[idx >> 7][idx & 127] = W[idx];
  if (tid < GROWS) dws[tid] = degw[row0 + tid];
  __syncthreads();
  for (int idx = tid; idx < GROWS * D; idx += 256) {
    const int r = idx >> 7;
    const float dw = dws[r];
    const float dinv = dw > 0.f ? 1.f / dw : 0.f;
    xs[r][idx & 127] = out[(size_t)(row0 + r) * D + (idx & 127)] * dinv;
  }
  __syncthreads();

  const int o = tid & 127;
  const int rh = tid >> 7;
  float acc[GROWS / 2];
#pragma unroll
  for (int j = 0; j < GROWS / 2; ++j) acc[j] = 0.f;
  for (int k = 0; k < D; ++k) {
    const float wv = Ws[o][k];
#pragma unroll
    for (int j = 0; j < GROWS / 2; ++j)
      acc[j] += xs[rh + 2 * j][k] * wv;
  }
  const float bias = b[o];
  __syncthreads();
#pragma unroll
  for (int j = 0; j < GROWS / 2; ++j)
    xs[rh + 2 * j][o] = acc[j] + bias;
  __syncthreads();

  const int w = tid >> 6, lane = tid & 63;
#pragma unroll
  for (int q = 0; q < 4; ++q) {
    const int r = w * 4 + q;
    const float2 v = *reinterpret_cast<const float2*>(&xs[r][lane * 2]);
    float ss = v.x * v.x + v.y * v.y;
#pragma unroll
    for (int off = 1; off < 64; off <<= 1) ss += __shfl_xor(ss, off);
    const float dw = dws[r];
    const float scale = (dw > 0.f) ? 1.f / fmaxf(sqrtf(ss), 1e-12f) : 0.f;
    *reinterpret_cast<float2*>(&out[(size_t)(row0 + r) * D + lane * 2]) =
        make_float2(v.x * scale, v.y * scale);
  }
}

// ---- fallback (tiny ws): atomic scatter, f32 path ----
__global__ __launch_bounds__(256) void scatter_kernel(
    const float* __restrict__ x, const int* __restrict__ rows,
    const int* __restrict__ cols, const float* __restrict__ ew,
    float* __restrict__ out, float* __restrict__ degw) {
  const int e = blockIdx.x * 4 + (threadIdx.x >> 6);
  const int lane = threadIdx.x & 63;
  if (e >= N_EDGES) return;
  const int r = rows[e];
  const int c = cols[e];
  const float w = ew[e];
  const float2 v = *reinterpret_cast<const float2*>(&x[(size_t)c * D + lane * 2]);
  atomicAdd(&out[(size_t)r * D + lane * 2], v.x * w);
  atomicAdd(&out[(size_t)r * D + lane * 2 + 1], v.y * w);
  if (lane == 0) atomicAdd(&degw[r], w);
}

extern "C" void kernel_launch(void* const* d_in, const int* in_sizes, int n_in,
                              void* d_out, int out_size, void* d_ws, size_t ws_size,
                              hipStream_t stream) {
  const float* x  = (const float*)d_in[0];
  const int*   ei = (const int*)d_in[1];
  const float* ew = (const float*)d_in[2];
  const float* W  = (const float*)d_in[3];
  const float* b  = (const float*)d_in[4];
  float* out = (float*)d_out;
  char* ws = (char*)d_ws;

  const int* rows = ei;
  const int* cols = ei + N_EDGES;

  // ws layout
  size_t off = 0;
  int* gcur = (int*)(ws + off);       off += ((size_t)NBUCK * 4 + 15) & ~(size_t)15;
  float* degw = (float*)(ws + off);   off += (size_t)N_NODES * 4;            // 80 KB
  unsigned* xb = (unsigned*)(ws + off); off += (size_t)N_NODES * (D / 2) * 4; // 5.12 MB
  uint2* bins = (uint2*)(ws + off);   off += (size_t)NBUCK * CAP * 8;        // 7.68 MB
  const size_t main_bytes = off;
  const size_t fallback_bytes = (((size_t)NBUCK * 4 + 15) & ~(size_t)15) + (size_t)N_NODES * 4;

  if (ws_size >= main_bytes) {
    zero_kernel<<<(NBUCK + 255) / 256, 256, 0, stream>>>(gcur, NBUCK);
    cast_kernel<<<(N_NODES * D / 4 + 255) / 256, 256, 0, stream>>>(x, xb);
    bin_kernel<<<NBLK1, 256, 0, stream>>>(rows, cols, ew, gcur, bins);
    agg_kernel<<<NBUCK, AGG_T, 0, stream>>>(xb, gcur, bins, out, degw);
    linear_norm_kernel<<<N_NODES / GROWS, 256, 0, stream>>>(W, b, degw, out);
  } else if (ws_size >= fallback_bytes) {
    hipMemsetAsync(out, 0, (size_t)N_NODES * D * 4, stream);
    hipMemsetAsync(degw, 0, (size_t)N_NODES * 4, stream);
    scatter_kernel<<<(N_EDGES + 3) / 4, 256, 0, stream>>>(x, rows, cols, ew, out, degw);
    linear_norm_kernel<<<N_NODES / GROWS, 256, 0, stream>>>(W, b, degw, out);
  }
}

// Round 5
// 75.791 us; speedup vs baseline: 2.5213x; 1.2132x over previous
//
#include <hip/hip_runtime.h>
#include <hip/hip_bf16.h>
#include <math.h>

#define N_NODES 20000
#define N_EDGES 640000
#define D 128

#define BSHIFT 5
#define BNODES 32
#define NBUCK 625                 // N_NODES >> BSHIFT
#define CAP 1536                  // per-bucket cap (mean 1024, sd ~31)
#define HNODES 16                 // nodes per agg half-block
#define HCAP 768                  // per-half cap (mean 512, sd ~23)
#define AGG_T 512
#define SRPT 3                    // ceil(CAP / AGG_T)
#define NBLK1 640
#define CHUNK 1000                // N_EDGES / NBLK1

#define GROWS 16                  // fallback linear kernel

typedef __attribute__((ext_vector_type(8))) short bf16x8;
typedef __attribute__((ext_vector_type(4))) float f32x4;

static __device__ __forceinline__ unsigned short f2bf(float f) {
  unsigned u = __float_as_uint(f);
  return (unsigned short)((u + 0x7fffu + ((u >> 16) & 1u)) >> 16);
}

// ---- cast x->bf16x2, W->bf16x2, zero gcur (all fused) ----
__global__ __launch_bounds__(256) void cast_kernel(
    const float* __restrict__ x, const float* __restrict__ W,
    unsigned* __restrict__ xb, unsigned* __restrict__ Wb,
    int* __restrict__ gcur) {
  const int i = blockIdx.x * 256 + threadIdx.x;
  if (i < N_NODES * D / 4) {
    const float4 v = *reinterpret_cast<const float4*>(&x[(size_t)i * 4]);
    uint2 o;
    o.x = (unsigned)f2bf(v.x) | ((unsigned)f2bf(v.y) << 16);
    o.y = (unsigned)f2bf(v.z) | ((unsigned)f2bf(v.w) << 16);
    *reinterpret_cast<uint2*>(&xb[(size_t)i * 2]) = o;
  }
  if (i < D * D / 4) {
    const float4 v = *reinterpret_cast<const float4*>(&W[(size_t)i * 4]);
    uint2 o;
    o.x = (unsigned)f2bf(v.x) | ((unsigned)f2bf(v.y) << 16);
    o.y = (unsigned)f2bf(v.z) | ((unsigned)f2bf(v.w) << 16);
    *reinterpret_cast<uint2*>(&Wb[(size_t)i * 2]) = o;
  }
  if (i < NBUCK) gcur[i] = 0;
}

// ---- phase 1: bin edges by node-bucket, contiguous bucket writes ----
__global__ __launch_bounds__(256) void bin_kernel(
    const int* __restrict__ rows, const int* __restrict__ cols,
    const float* __restrict__ ew, int* __restrict__ gcur,
    uint2* __restrict__ bins) {
  __shared__ int cnt[NBUCK];
  __shared__ int base[NBUCK];
  const int tid = threadIdx.x;
  const int e0 = blockIdx.x * CHUNK;
  const int e1 = min(e0 + CHUNK, N_EDGES);
  for (int i = tid; i < NBUCK; i += 256) cnt[i] = 0;
  __syncthreads();
  for (int e = e0 + tid; e < e1; e += 256)
    atomicAdd(&cnt[rows[e] >> BSHIFT], 1);
  __syncthreads();
  for (int i = tid; i < NBUCK; i += 256) {
    const int c = cnt[i];
    base[i] = c ? atomicAdd(&gcur[i], c) : 0;
  }
  __syncthreads();
  for (int i = tid; i < NBUCK; i += 256) cnt[i] = 0;
  __syncthreads();
  for (int e = e0 + tid; e < e1; e += 256) {
    const int r = rows[e];
    const int b = r >> BSHIFT;
    const int p = base[b] + atomicAdd(&cnt[b], 1);
    if (p < CAP)
      bins[(size_t)b * CAP + p] =
          make_uint2(((unsigned)(r & (BNODES - 1)) << 16) | (unsigned)cols[e],
                     __float_as_uint(ew[e]));
  }
}

// ---- phase 2: half-bucket LDS counting sort + bf16 gather, writes bf16 MEAN ----
__global__ __launch_bounds__(AGG_T) void agg_kernel(
    const unsigned* __restrict__ xb, const int* __restrict__ gcur,
    const uint2* __restrict__ bins, unsigned* __restrict__ aggb,
    float* __restrict__ degw) {
  __shared__ uint2 list[HCAP];
  __shared__ int cnt[HNODES];
  __shared__ int base[HNODES];
  const int b = blockIdx.x >> 1;
  const int half = blockIdx.x & 1;
  const int tid = threadIdx.x;
  const int n = min(gcur[b], CAP);
  if (tid < HNODES) cnt[tid] = 0;
  __syncthreads();

  uint2 ebuf[SRPT];
  int rkbuf[SRPT], rlbuf[SRPT];
#pragma unroll
  for (int j = 0; j < SRPT; ++j) {
    const int i = tid + j * AGG_T;
    rlbuf[j] = -1;
    if (i < n) {
      const uint2 e = bins[(size_t)b * CAP + i];
      const int rl = (int)(e.x >> 16);
      if ((rl >> 4) == half) {
        ebuf[j] = e;
        rlbuf[j] = rl & 15;
        rkbuf[j] = atomicAdd(&cnt[rl & 15], 1);
      }
    }
  }
  __syncthreads();
  if (tid < 64) {  // wave-parallel prefix scan over 16 counters
    const int c = (tid < HNODES) ? cnt[tid] : 0;
    int s = c;
#pragma unroll
    for (int off = 1; off < HNODES; off <<= 1) {
      const int t = __shfl_up(s, off);
      if (tid >= off) s += t;
    }
    if (tid < HNODES) base[tid] = s - c;
  }
  __syncthreads();
#pragma unroll
  for (int j = 0; j < SRPT; ++j)
    if (rlbuf[j] >= 0) {
      const int p = base[rlbuf[j]] + rkbuf[j];
      if (p < HCAP) list[p] = ebuf[j];
    }
  __syncthreads();

  // 8 waves x 2 nodes each; lane owns one bf16x2 word of 128 features
  const int wv = tid >> 6, lane = tid & 63;
  for (int q = 0; q < 2; ++q) {
    const int rl = wv * 2 + q;
    const int node = (b << BSHIFT) + half * HNODES + rl;
    const int s = base[rl];
    const int ke = min(s + cnt[rl], HCAP);
    float a0 = 0.f, a1 = 0.f, dw = 0.f;
    for (int k = s; k < ke; k += 16) {  // 16 gathers in flight, branchless tail
      unsigned v[16];
      float w[16];
#pragma unroll
      for (int u = 0; u < 16; ++u) {
        int idx = k + u;
        const bool ok = idx < ke;
        if (!ok) idx = ke - 1;
        const uint2 e = list[idx];
        w[u] = ok ? __uint_as_float(e.y) : 0.f;
        v[u] = xb[(size_t)(e.x & 0xffffu) * (D / 2) + lane];
      }
#pragma unroll
      for (int u = 0; u < 16; ++u) {
        a0 += __uint_as_float(v[u] << 16) * w[u];
        a1 += __uint_as_float(v[u] & 0xffff0000u) * w[u];
        dw += w[u];
      }
    }
    const float dinv = dw > 0.f ? 1.f / dw : 0.f;
    if (lane == 0) degw[node] = dw;
    aggb[(size_t)node * (D / 2) + lane] =
        (unsigned)f2bf(a0 * dinv) | ((unsigned)f2bf(a1 * dinv) << 16);
  }
}

// ---- MFMA: out = normalize(mean_agg @ W^T + b), no LDS ----
__global__ __launch_bounds__(256) void gemm_norm_kernel(
    const unsigned* __restrict__ aggb, const unsigned* __restrict__ Wb,
    const float* __restrict__ bias, const float* __restrict__ degw,
    float* __restrict__ out) {
  const int wv = threadIdx.x >> 6;
  const int lane = threadIdx.x & 63;
  const int row0 = blockIdx.x * 64 + wv * 16;
  // A frag: row = lane&15, k = kk*32 + (lane>>4)*8 + e
  const int arow = row0 + (lane & 15);
  const int asafe = arow < N_NODES ? arow : N_NODES - 1;
  const int koff = (lane >> 4) * 4;

  bf16x8 a[4];
#pragma unroll
  for (int kk = 0; kk < 4; ++kk) {
    union { uint4 u; bf16x8 v; } cv;
    cv.u = *reinterpret_cast<const uint4*>(
        &aggb[(size_t)asafe * (D / 2) + kk * 16 + koff]);
    a[kk] = cv.v;
  }

  f32x4 acc[8];
#pragma unroll
  for (int t = 0; t < 8; ++t) {
    const int o = t * 16 + (lane & 15);  // B col j = lane&15 -> out col
    f32x4 c = {0.f, 0.f, 0.f, 0.f};
#pragma unroll
    for (int kk = 0; kk < 4; ++kk) {
      union { uint4 u; bf16x8 v; } cv;
      cv.u = *reinterpret_cast<const uint4*>(
          &Wb[(size_t)o * (D / 2) + kk * 16 + koff]);
      c = __builtin_amdgcn_mfma_f32_16x16x32_bf16(a[kk], cv.v, c, 0, 0, 0);
    }
    acc[t] = c;
  }

  // bias + per-row sum-of-squares (row = (lane>>4)*4 + reg)
  float ss[4] = {0.f, 0.f, 0.f, 0.f};
#pragma unroll
  for (int t = 0; t < 8; ++t) {
    const float bc = bias[t * 16 + (lane & 15)];
#pragma unroll
    for (int r = 0; r < 4; ++r) {
      const float y = acc[t][r] + bc;
      acc[t][r] = y;
      ss[r] += y * y;
    }
  }
#pragma unroll
  for (int r = 0; r < 4; ++r) {
#pragma unroll
    for (int off = 1; off < 16; off <<= 1)
      ss[r] += __shfl_xor(ss[r], off);
  }
  float scale[4];
#pragma unroll
  for (int r = 0; r < 4; ++r) {
    const int row = row0 + (lane >> 4) * 4 + r;
    const float dw = (row < N_NODES) ? degw[row] : 0.f;
    scale[r] = (dw > 0.f) ? 1.f / fmaxf(sqrtf(ss[r]), 1e-12f) : 0.f;
  }
#pragma unroll
  for (int t = 0; t < 8; ++t) {
#pragma unroll
    for (int r = 0; r < 4; ++r) {
      const int row = row0 + (lane >> 4) * 4 + r;
      if (row < N_NODES)
        out[(size_t)row * D + t * 16 + (lane & 15)] = acc[t][r] * scale[r];
    }
  }
}

// ---- fallback path (tiny ws): f32 scatter + f32 GEMV/norm ----
__global__ __launch_bounds__(256) void scatter_kernel(
    const float* __restrict__ x, const int* __restrict__ rows,
    const int* __restrict__ cols, const float* __restrict__ ew,
    float* __restrict__ out, float* __restrict__ degw) {
  const int e = blockIdx.x * 4 + (threadIdx.x >> 6);
  const int lane = threadIdx.x & 63;
  if (e >= N_EDGES) return;
  const int r = rows[e];
  const int c = cols[e];
  const float w = ew[e];
  const float2 v = *reinterpret_cast<const float2*>(&x[(size_t)c * D + lane * 2]);
  atomicAdd(&out[(size_t)r * D + lane * 2], v.x * w);
  atomicAdd(&out[(size_t)r * D + lane * 2 + 1], v.y * w);
  if (lane == 0) atomicAdd(&degw[r], w);
}

__global__ __launch_bounds__(256) void linear_norm_kernel(
    const float* __restrict__ W, const float* __restrict__ b,
    const float* __restrict__ degw, float* __restrict__ out) {
  __shared__ float Ws[D][D + 1];
  __shared__ float xs[GROWS][D];
  __shared__ float dws[GROWS];
  const int tid = threadIdx.x;
  const int row0 = blockIdx.x * GROWS;
  for (int idx = tid; idx < D * D; idx += 256)
    Ws[idx >> 7][idx & 127] = W[idx];
  if (tid < GROWS) dws[tid] = degw[row0 + tid];
  __syncthreads();
  for (int idx = tid; idx < GROWS * D; idx += 256) {
    const int r = idx >> 7;
    const float dw = dws[r];
    const float dinv = dw > 0.f ? 1.f / dw : 0.f;
    xs[r][idx & 127] = out[(size_t)(row0 + r) * D + (idx & 127)] * dinv;
  }
  __syncthreads();
  const int o = tid & 127;
  const int rh = tid >> 7;
  float acc[GROWS / 2];
#pragma unroll
  for (int j = 0; j < GROWS / 2; ++j) acc[j] = 0.f;
  for (int k = 0; k < D; ++k) {
    const float wv = Ws[o][k];
#pragma unroll
    for (int j = 0; j < GROWS / 2; ++j)
      acc[j] += xs[rh + 2 * j][k] * wv;
  }
  const float bias = b[o];
  __syncthreads();
#pragma unroll
  for (int j = 0; j < GROWS / 2; ++j)
    xs[rh + 2 * j][o] = acc[j] + bias;
  __syncthreads();
  const int w = tid >> 6, lane = tid & 63;
#pragma unroll
  for (int q = 0; q < 4; ++q) {
    const int r = w * 4 + q;
    const float2 v = *reinterpret_cast<const float2*>(&xs[r][lane * 2]);
    float ss = v.x * v.x + v.y * v.y;
#pragma unroll
    for (int off = 1; off < 64; off <<= 1) ss += __shfl_xor(ss, off);
    const float dw = dws[r];
    const float scale = (dw > 0.f) ? 1.f / fmaxf(sqrtf(ss), 1e-12f) : 0.f;
    *reinterpret_cast<float2*>(&out[(size_t)(row0 + r) * D + lane * 2]) =
        make_float2(v.x * scale, v.y * scale);
  }
}

extern "C" void kernel_launch(void* const* d_in, const int* in_sizes, int n_in,
                              void* d_out, int out_size, void* d_ws, size_t ws_size,
                              hipStream_t stream) {
  const float* x  = (const float*)d_in[0];
  const int*   ei = (const int*)d_in[1];
  const float* ew = (const float*)d_in[2];
  const float* W  = (const float*)d_in[3];
  const float* b  = (const float*)d_in[4];
  float* out = (float*)d_out;
  char* ws = (char*)d_ws;

  const int* rows = ei;
  const int* cols = ei + N_EDGES;

  // ws layout
  size_t off = 0;
  int* gcur = (int*)(ws + off);        off += ((size_t)NBUCK * 4 + 15) & ~(size_t)15;
  float* degw = (float*)(ws + off);    off += (size_t)N_NODES * 4;              // 80 KB
  unsigned* xb = (unsigned*)(ws + off);  off += (size_t)N_NODES * (D / 2) * 4;  // 5.12 MB
  unsigned* Wb = (unsigned*)(ws + off);  off += (size_t)D * (D / 2) * 4;        // 32 KB
  unsigned* aggb = (unsigned*)(ws + off); off += (size_t)N_NODES * (D / 2) * 4; // 5.12 MB
  uint2* bins = (uint2*)(ws + off);    off += (size_t)NBUCK * CAP * 8;          // 7.68 MB
  const size_t main_bytes = off;
  const size_t fallback_bytes = (((size_t)NBUCK * 4 + 15) & ~(size_t)15) + (size_t)N_NODES * 4;

  if (ws_size >= main_bytes) {
    cast_kernel<<<(N_NODES * D / 4 + 255) / 256, 256, 0, stream>>>(x, W, xb, Wb, gcur);
    bin_kernel<<<NBLK1, 256, 0, stream>>>(rows, cols, ew, gcur, bins);
    agg_kernel<<<NBUCK * 2, AGG_T, 0, stream>>>(xb, gcur, bins, aggb, degw);
    gemm_norm_kernel<<<(N_NODES + 63) / 64, 256, 0, stream>>>(aggb, Wb, b, degw, out);
  } else if (ws_size >= fallback_bytes) {
    hipMemsetAsync(out, 0, (size_t)N_NODES * D * 4, stream);
    hipMemsetAsync(degw, 0, (size_t)N_NODES * 4, stream);
    scatter_kernel<<<(N_EDGES + 3) / 4, 256, 0, stream>>>(x, rows, cols, ew, out, degw);
    linear_norm_kernel<<<N_NODES / GROWS, 256, 0, stream>>>(W, b, degw, out);
  }
}